// Round 2
// baseline (9795.149 us; speedup 1.0000x reference)
//
#include <hip/hip_runtime.h>
#include <hip/hip_bf16.h>

#define ND 30000
#define NT 15000
#define FD 200
#define FT 570
#define HDIM 768
#define EDD 300000
#define EDT 400000
#define ETT 200000

// ---------------- dtype-adaptive load/store ----------------
// flag (in ws): 0 = harness float tensors are bf16, 1 = they are fp32.

__device__ __forceinline__ float ldx(const void* p, size_t i, int f32) {
  return f32 ? ((const float*)p)[i]
             : __bfloat162float(((const __hip_bfloat16*)p)[i]);
}
__device__ __forceinline__ void stx(void* p, size_t i, int f32, float v) {
  if (f32) ((float*)p)[i] = v;
  else     ((__hip_bfloat16*)p)[i] = __float2bfloat16(v);
}

__device__ __forceinline__ float wave_reduce(float v) {
#pragma unroll
  for (int off = 32; off > 0; off >>= 1) v += __shfl_xor(v, off, 64);
  return v;
}

// ---------------- dtype sniffer ----------------
// Read first 8192 elements of x as bf16. True bf16 N(0,1): 0 outliers.
// fp32 reinterpreted: ~half the 16-bit words have garbage exponents -> ~4000.
__global__ void sniff(const void* x, int* flag) {
  int t = threadIdx.x;
  float cnt = 0.f;
  for (int i = t; i < 8192; i += 256) {
    float v = __bfloat162float(((const __hip_bfloat16*)x)[i]);
    if (!(fabsf(v) < 100.f)) cnt += 1.f;  // true for NaN too
  }
  cnt = wave_reduce(cnt);
  __shared__ float red[4];
  if ((t & 63) == 0) red[t >> 6] = cnt;
  __syncthreads();
  if (t == 0) flag[0] = (red[0] + red[1] + red[2] + red[3] > 256.f) ? 1 : 0;
}

// ---------------- va[k] = sum_h W[k,h]*a[h], one wave per k ----------------
__global__ __launch_bounds__(256) void wa_dot(const void* __restrict__ W, const void* __restrict__ a,
                                              float* __restrict__ outv, int fin,
                                              const int* __restrict__ flag) {
  int f32 = flag[0];
  int k = (blockIdx.x * 256 + threadIdx.x) >> 6;
  int lane = threadIdx.x & 63;
  if (k >= fin) return;
  float acc = 0.f;
  for (int h = lane; h < HDIM; h += 64)
    acc += ldx(W, (size_t)k * HDIM + h, f32) * ldx(a, h, f32);
  acc = wave_reduce(acc);
  if (lane == 0) outv[k] = acc;
}

// ---------------- out[row] = dot(x_eff[row,:], va), one wave per row -------
// x_eff[row,k] = (mask && mask[row]) ? tok[k] : x[row,k]
__global__ __launch_bounds__(256) void row_dot(const void* __restrict__ x,
                                               const int* __restrict__ mask,
                                               const void* __restrict__ tok,
                                               const float* __restrict__ va,
                                               float* __restrict__ outv, int N, int K,
                                               const int* __restrict__ flag) {
  int f32 = flag[0];
  int row = (blockIdx.x * 256 + threadIdx.x) >> 6;
  int lane = threadIdx.x & 63;
  if (row >= N) return;
  bool msk = (mask != nullptr) && (mask[row] != 0);
  float acc = 0.f;
  for (int k = lane; k < K; k += 64) {
    float v = msk ? ldx(tok, k, f32) : ldx(x, (size_t)row * K + k, f32);
    acc += v * va[k];
  }
  acc = wave_reduce(acc);
  if (lane == 0) outv[row] = acc;
}

// ---------------- C[M,N](bf16) = A_eff[M,K] @ B[K,N] ----------------
#define TM 64
#define TN 64
#define TK 16
__global__ __launch_bounds__(256) void gemm_tile(const void* __restrict__ A,
                                                 const int* __restrict__ mask,
                                                 const void* __restrict__ tok,
                                                 const void* __restrict__ B,
                                                 __hip_bfloat16* __restrict__ C,
                                                 int M, int N, int K,
                                                 const int* __restrict__ flag) {
  int f32 = flag[0];
  __shared__ float As[TK][TM + 4];
  __shared__ float Bs[TK][TN + 4];
  int t = threadIdx.x;
  int m0 = blockIdx.y * TM;
  int n0 = blockIdx.x * TN;
  int tm = (t & 15) * 4;
  int tn = (t >> 4) * 4;
  float acc[4][4] = {{0.f}};
  for (int k0 = 0; k0 < K; k0 += TK) {
#pragma unroll
    for (int i = 0; i < 4; ++i) {
      int lin = t + i * 256;            // covers TM*TK, m-major
      int m = lin / TK;
      int kk = lin % TK;
      int gm = m0 + m, gk = k0 + kk;
      float v = 0.f;
      if (gm < M && gk < K) {
        bool msk = (mask != nullptr) && (mask[gm] != 0);
        v = msk ? ldx(tok, gk, f32) : ldx(A, (size_t)gm * K + gk, f32);
      }
      As[kk][m] = v;
    }
#pragma unroll
    for (int i = 0; i < 4; ++i) {
      int lin = t + i * 256;            // covers TK*TN, kk-major
      int kk = lin / TN;
      int n = lin % TN;
      int gk = k0 + kk;
      float v = 0.f;
      if (gk < K) v = ldx(B, (size_t)gk * N + (n0 + n), f32);
      Bs[kk][n] = v;
    }
    __syncthreads();
#pragma unroll
    for (int kk = 0; kk < TK; ++kk) {
      float a0 = As[kk][tm + 0], a1 = As[kk][tm + 1], a2 = As[kk][tm + 2], a3 = As[kk][tm + 3];
      float b0 = Bs[kk][tn + 0], b1 = Bs[kk][tn + 1], b2 = Bs[kk][tn + 2], b3 = Bs[kk][tn + 3];
      acc[0][0] += a0 * b0; acc[0][1] += a0 * b1; acc[0][2] += a0 * b2; acc[0][3] += a0 * b3;
      acc[1][0] += a1 * b0; acc[1][1] += a1 * b1; acc[1][2] += a1 * b2; acc[1][3] += a1 * b3;
      acc[2][0] += a2 * b0; acc[2][1] += a2 * b1; acc[2][2] += a2 * b2; acc[2][3] += a2 * b3;
      acc[3][0] += a3 * b0; acc[3][1] += a3 * b1; acc[3][2] += a3 * b2; acc[3][3] += a3 * b3;
    }
    __syncthreads();
  }
#pragma unroll
  for (int i = 0; i < 4; ++i) {
    int gm = m0 + tm + i;
    if (gm < M) {
#pragma unroll
      for (int j = 0; j < 4; ++j)
        C[(size_t)gm * N + n0 + tn + j] = __float2bfloat16(acc[i][j]);
    }
  }
}

// ---------------- misc small kernels ----------------
__global__ void zero_f32(float* __restrict__ p, int n) {
  int i = blockIdx.x * 256 + threadIdx.x;
  if (i < n) p[i] = 0.f;
}

__global__ void init_bias(float* __restrict__ acc, const void* __restrict__ b1,
                          const void* __restrict__ b2, int total, const int* __restrict__ flag) {
  int f32 = flag[0];
  int i = blockIdx.x * 256 + threadIdx.x;
  if (i >= total) return;
  int h = i % HDIM;
  acc[i] = ldx(b1, h, f32) + ldx(b2, h, f32);
}

// w[e] = exp(leaky_relu(es[src]+ed[dst])); s[dst] += w[e]
__global__ void edge_w(const int* __restrict__ src, const int* __restrict__ dst, int E, int nself,
                       const float* __restrict__ es, const float* __restrict__ ed,
                       float* __restrict__ w, float* __restrict__ s) {
  int i = blockIdx.x * 256 + threadIdx.x;
  if (i >= E + nself) return;
  int si, di;
  if (i < E) { si = src[i]; di = dst[i]; } else { si = di = i - E; }
  float e = es[si] + ed[di];
  e = (e >= 0.f) ? e : 0.2f * e;   // leaky_relu, slope 0.2
  float wv = __expf(e);
  w[i] = wv;
  atomicAdd(&s[di], wv);
}

// one wave per edge: acc[dst,:] += (w/s) * hs[src,:]
__global__ __launch_bounds__(256) void edge_scatter(const int* __restrict__ src, const int* __restrict__ dst,
                                                    int E, int nself,
                                                    const float* __restrict__ w, const float* __restrict__ s,
                                                    const __hip_bfloat16* __restrict__ hs,
                                                    float* __restrict__ acc) {
  int gid = blockIdx.x * 256 + threadIdx.x;
  int wid = gid >> 6;
  int lane = threadIdx.x & 63;
  if (wid >= E + nself) return;
  int si, di;
  if (wid < E) { si = src[wid]; di = dst[wid]; } else { si = di = wid - E; }
  float alpha = w[wid] / (s[di] + 1e-16f);
  const __hip_bfloat16* hrow = hs + (size_t)si * HDIM;
  float* arow = acc + (size_t)di * HDIM;
#pragma unroll
  for (int j = 0; j < HDIM / 64; ++j) {
    int h = lane + j * 64;
    atomicAdd(&arow[h], alpha * __bfloat162float(hrow[h]));
  }
}

// layer-1 output: relu; non-finite -> 3000.0 diagnostic marker
__global__ void finalize1(const float* __restrict__ acc, void* __restrict__ out, size_t base,
                          int total, const int* __restrict__ flag) {
  int i = blockIdx.x * 256 + threadIdx.x;
  if (i >= total) return;
  float v = acc[i];
  float r = (v > 0.f) ? v : 0.f;
  if (!(fabsf(v) < 1e30f)) r = 3000.0f;   // NaN/Inf diagnostic
  stx(out, base + i, flag[0], r);
}

// layer-2: relu, masked squared diff vs layer-1 output
__global__ __launch_bounds__(256) void finalize2(const float* __restrict__ acc,
                                                 const void* __restrict__ out, size_t base,
                                                 const int* __restrict__ mask,
                                                 float* __restrict__ parts, int total,
                                                 const int* __restrict__ flag) {
  int f32 = flag[0];
  int i = blockIdx.x * 256 + threadIdx.x;
  float c = 0.f;
  if (i < total) {
    float v = acc[i];
    v = (v > 0.f) ? v : 0.f;
    if (mask[i / HDIM] != 0) {
      float d = ldx(out, base + i, f32) - v;
      c = d * d;
    }
  }
  c = wave_reduce(c);
  __shared__ float red[4];
  if ((threadIdx.x & 63) == 0) red[threadIdx.x >> 6] = c;
  __syncthreads();
  if (threadIdx.x == 0)
    atomicAdd(&parts[blockIdx.x & 2047], red[0] + red[1] + red[2] + red[3]);
}

__global__ void mask_count(const int* __restrict__ mask, int n, float* __restrict__ cnt) {
  int i = blockIdx.x * 256 + threadIdx.x;
  float v = (i < n && mask[i] != 0) ? 1.f : 0.f;
  v = wave_reduce(v);
  __shared__ float red[4];
  if ((threadIdx.x & 63) == 0) red[threadIdx.x >> 6] = v;
  __syncthreads();
  if (threadIdx.x == 0) atomicAdd(cnt, red[0] + red[1] + red[2] + red[3]);
}

__global__ __launch_bounds__(256) void loss_final(const float* __restrict__ parts,
                                                  const float* __restrict__ cnts,
                                                  void* __restrict__ out, size_t off,
                                                  const int* __restrict__ flag) {
  float a = 0.f, b = 0.f;
  for (int i = threadIdx.x; i < 2048; i += 256) { a += parts[i]; b += parts[2048 + i]; }
  a = wave_reduce(a);
  b = wave_reduce(b);
  __shared__ float ra[4], rb[4];
  if ((threadIdx.x & 63) == 0) { ra[threadIdx.x >> 6] = a; rb[threadIdx.x >> 6] = b; }
  __syncthreads();
  if (threadIdx.x == 0) {
    float sd = ra[0] + ra[1] + ra[2] + ra[3];
    float st = rb[0] + rb[1] + rb[2] + rb[3];
    float loss = sd / (cnts[0] * (float)HDIM + 1e-16f) + st / (cnts[1] * (float)HDIM + 1e-16f);
    stx(out, off, flag[0], loss);
  }
}

// ---------------- host ----------------

extern "C" void kernel_launch(void* const* d_in, const int* in_sizes, int n_in,
                              void* d_out, int out_size, void* d_ws, size_t ws_size,
                              hipStream_t stream) {
  const void* drug_x    = d_in[0];
  const void* target_x  = d_in[1];
  const int* dd_src = (const int*)d_in[2];
  const int* dd_dst = (const int*)d_in[3];
  const int* dt_src = (const int*)d_in[4];
  const int* dt_dst = (const int*)d_in[5];
  const int* tt_src = (const int*)d_in[6];
  const int* tt_dst = (const int*)d_in[7];
  const int* drug_mask   = (const int*)d_in[8];
  const int* target_mask = (const int*)d_in[9];
  const void* mask_drug   = d_in[10];
  const void* mask_target = d_in[11];
  const void* Wsrc_dd = d_in[12];
  const void* Wdst_dd = d_in[13];
  const void* asrc_dd = d_in[14];
  const void* adst_dd = d_in[15];
  const void* b_dd    = d_in[16];
  const void* Wsrc_dt = d_in[17];
  const void* Wdst_dt = d_in[18];
  const void* asrc_dt = d_in[19];
  const void* adst_dt = d_in[20];
  const void* b_dt    = d_in[21];
  const void* Wsrc_rv = d_in[22];
  const void* Wdst_rv = d_in[23];
  const void* asrc_rv = d_in[24];
  const void* adst_rv = d_in[25];
  const void* b_rv    = d_in[26];
  const void* Wsrc_tt = d_in[27];
  const void* Wdst_tt = d_in[28];
  const void* asrc_tt = d_in[29];
  const void* adst_tt = d_in[30];
  const void* b_tt    = d_in[31];

  // workspace bump allocator (256B aligned)
  char* p = (char*)d_ws;
  auto alloc = [&](size_t bytes) -> void* {
    void* r = (void*)p;
    p += (bytes + 255) & ~(size_t)255;
    return r;
  };
  float* acc_d = (float*)alloc((size_t)ND * HDIM * 4);            // 92.2 MB
  float* acc_t = (float*)alloc((size_t)NT * HDIM * 4);            // 46.1 MB
  __hip_bfloat16* hs = (__hip_bfloat16*)alloc((size_t)ND * HDIM * 2); // 46.1 MB
  float* es    = (float*)alloc((size_t)ND * 4);
  float* ed    = (float*)alloc((size_t)ND * 4);
  float* sden  = (float*)alloc((size_t)ND * 4);
  float* wedge = (float*)alloc((size_t)430000 * 4);
  float* vabuf = (float*)alloc((size_t)3080 * 4);
  float* parts = (float*)alloc((size_t)(4096 + 2) * 4);  // [2048 d][2048 t][cnt_d][cnt_t]
  float* cnts  = parts + 4096;
  int*   flag  = (int*)alloc(256);

  // 1) dtype sniff (everything downstream branches on flag[0])
  sniff<<<1, 256, 0, stream>>>(drug_x, flag);

  // 2) zero loss partials + counters
  zero_f32<<<(4098 + 255) / 256, 256, 0, stream>>>(parts, 4098);

  // 3) va = W @ a for all 8 (relation x src/dst)
  struct { const void* W; const void* a; int fin; int off; } vas[8] = {
    {Wsrc_dd, asrc_dd, FD, 0},    {Wdst_dd, adst_dd, FD, 200},
    {Wsrc_dt, asrc_dt, FD, 400},  {Wdst_dt, adst_dt, FT, 600},
    {Wsrc_rv, asrc_rv, FT, 1170}, {Wdst_rv, adst_rv, FD, 1740},
    {Wsrc_tt, asrc_tt, FT, 1940}, {Wdst_tt, adst_tt, FT, 2510},
  };
  for (int i = 0; i < 8; ++i)
    wa_dot<<<(vas[i].fin * 64 + 255) / 256, 256, 0, stream>>>(vas[i].W, vas[i].a,
                                                              vabuf + vas[i].off, vas[i].fin, flag);

  mask_count<<<(ND + 255) / 256, 256, 0, stream>>>(drug_mask, ND, cnts + 0);
  mask_count<<<(NT + 255) / 256, 256, 0, stream>>>(target_mask, NT, cnts + 1);

  // one GAT relation: scores, hs GEMM, softmax-scatter into acc
  auto run_rel = [&](const void* xs, const int* mk_s, const void* tok_s, int Ns, int fs,
                     const void* xd, const int* mk_d, const void* tok_d, int Nd, int fd,
                     const void* Wsrc, const float* vas_, const float* vad_,
                     const int* srcI, const int* dstI, int E, int nself, float* acc) {
    row_dot<<<(Ns + 3) / 4, 256, 0, stream>>>(xs, mk_s, tok_s, vas_, es, Ns, fs, flag);
    row_dot<<<(Nd + 3) / 4, 256, 0, stream>>>(xd, mk_d, tok_d, vad_, ed, Nd, fd, flag);
    dim3 gg(HDIM / TN, (Ns + TM - 1) / TM);
    gemm_tile<<<gg, 256, 0, stream>>>(xs, mk_s, tok_s, Wsrc, hs, Ns, HDIM, fs, flag);
    zero_f32<<<(Nd + 255) / 256, 256, 0, stream>>>(sden, Nd);
    int ET = E + nself;
    edge_w<<<(ET + 255) / 256, 256, 0, stream>>>(srcI, dstI, E, nself, es, ed, wedge, sden);
    edge_scatter<<<(ET + 3) / 4, 256, 0, stream>>>(srcI, dstI, E, nself, wedge, sden, hs, acc);
  };

  auto run_layer = [&](const int* dmk, const int* tmk) {
    // masks nullptr => layer 1 (original features); else mask-token substitution
    const int* mD = dmk; const int* mT = tmk;
    init_bias<<<(ND * HDIM + 255) / 256, 256, 0, stream>>>(acc_d, b_dd, b_rv, ND * HDIM, flag);
    init_bias<<<(NT * HDIM + 255) / 256, 256, 0, stream>>>(acc_t, b_dt, b_tt, NT * HDIM, flag);
    // d-d (with self loops)
    run_rel(drug_x, mD, mask_drug, ND, FD, drug_x, mD, mask_drug, ND, FD,
            Wsrc_dd, vabuf + 0, vabuf + 200, dd_src, dd_dst, EDD, ND, acc_d);
    // rev(d-t): target -> drug, edges (dt_dst -> dt_src)
    run_rel(target_x, mT, mask_target, NT, FT, drug_x, mD, mask_drug, ND, FD,
            Wsrc_rv, vabuf + 1170, vabuf + 1740, dt_dst, dt_src, EDT, 0, acc_d);
    // d-t: drug -> target
    run_rel(drug_x, mD, mask_drug, ND, FD, target_x, mT, mask_target, NT, FT,
            Wsrc_dt, vabuf + 400, vabuf + 600, dt_src, dt_dst, EDT, 0, acc_t);
    // t-t (with self loops)
    run_rel(target_x, mT, mask_target, NT, FT, target_x, mT, mask_target, NT, FT,
            Wsrc_tt, vabuf + 1940, vabuf + 2510, tt_src, tt_dst, ETT, NT, acc_t);
  };

  void* out = d_out;
  size_t baseT = (size_t)ND * HDIM;
  size_t baseL = (size_t)ND * HDIM + (size_t)NT * HDIM;

  // ---- layer 1 (original features) ----
  run_layer(nullptr, nullptr);
  finalize1<<<(ND * HDIM + 255) / 256, 256, 0, stream>>>(acc_d, out, 0, ND * HDIM, flag);
  finalize1<<<(NT * HDIM + 255) / 256, 256, 0, stream>>>(acc_t, out, baseT, NT * HDIM, flag);

  // ---- layer 2 (masked features) + fused loss ----
  run_layer(drug_mask, target_mask);
  finalize2<<<(ND * HDIM + 255) / 256, 256, 0, stream>>>(acc_d, out, 0, drug_mask, parts,
                                                         ND * HDIM, flag);
  finalize2<<<(NT * HDIM + 255) / 256, 256, 0, stream>>>(acc_t, out, baseT, target_mask,
                                                         parts + 2048, NT * HDIM, flag);
  loss_final<<<1, 256, 0, stream>>>(parts, cnts, out, baseL, flag);
}

// Round 3
// 3893.605 us; speedup vs baseline: 2.5157x; 2.5157x over previous
//
#include <hip/hip_runtime.h>
#include <hip/hip_bf16.h>

#define ND 30000
#define NT 15000
#define FD 200
#define FT 570
#define HDIM 768
#define EDD 300000
#define EDT 400000
#define ETT 200000

// ---------------- dtype-adaptive load/store ----------------
// flag[0]: 0 = harness float tensors are bf16, 1 = fp32.

__device__ __forceinline__ float ldx(const void* p, size_t i, int f32) {
  return f32 ? ((const float*)p)[i]
             : __bfloat162float(((const __hip_bfloat16*)p)[i]);
}
__device__ __forceinline__ void stx(void* p, size_t i, int f32, float v) {
  if (f32) ((float*)p)[i] = v;
  else     ((__hip_bfloat16*)p)[i] = __float2bfloat16(v);
}
__device__ __forceinline__ float b2f(unsigned short u) {
  return __uint_as_float(((unsigned)u) << 16);
}

__device__ __forceinline__ float wave_reduce(float v) {
#pragma unroll
  for (int off = 32; off > 0; off >>= 1) v += __shfl_xor(v, off, 64);
  return v;
}

// ---------------- dtype sniffer ----------------
__global__ void sniff(const void* x, int* flag) {
  int t = threadIdx.x;
  float cnt = 0.f;
  for (int i = t; i < 8192; i += 256) {
    float v = __bfloat162float(((const __hip_bfloat16*)x)[i]);
    if (!(fabsf(v) < 100.f)) cnt += 1.f;  // true for NaN too
  }
  cnt = wave_reduce(cnt);
  __shared__ float red[4];
  if ((t & 63) == 0) red[t >> 6] = cnt;
  __syncthreads();
  if (t == 0) flag[0] = (red[0] + red[1] + red[2] + red[3] > 256.f) ? 1 : 0;
}

// ---------------- va[k] = sum_h W[k,h]*a[h], one wave per k ----------------
__global__ __launch_bounds__(256) void wa_dot(const void* __restrict__ W, const void* __restrict__ a,
                                              float* __restrict__ outv, int fin,
                                              const int* __restrict__ flag) {
  int f32 = flag[0];
  int k = (blockIdx.x * 256 + threadIdx.x) >> 6;
  int lane = threadIdx.x & 63;
  if (k >= fin) return;
  float acc = 0.f;
  for (int h = lane; h < HDIM; h += 64)
    acc += ldx(W, (size_t)k * HDIM + h, f32) * ldx(a, h, f32);
  acc = wave_reduce(acc);
  if (lane == 0) outv[k] = acc;
}

// ---------- 4 dots per row (shared x read), one wave per row ----------
// outv[row*4 + j] = dot(x_eff[row,:], va[j*K:...]),  x_eff = mask-token substituted
__global__ __launch_bounds__(256) void row_dot4(const void* __restrict__ x,
                                                const int* __restrict__ mask,
                                                const void* __restrict__ tok,
                                                const float* __restrict__ va,
                                                float* __restrict__ outv, int N, int K,
                                                const int* __restrict__ flag) {
  int f32 = flag[0];
  int row = (blockIdx.x * 256 + threadIdx.x) >> 6;
  int lane = threadIdx.x & 63;
  if (row >= N) return;
  bool msk = (mask != nullptr) && (mask[row] != 0);
  float a0 = 0.f, a1 = 0.f, a2 = 0.f, a3 = 0.f;
  for (int k = lane; k < K; k += 64) {
    float v = msk ? ldx(tok, k, f32) : ldx(x, (size_t)row * K + k, f32);
    a0 += v * va[k];
    a1 += v * va[K + k];
    a2 += v * va[2 * K + k];
    a3 += v * va[3 * K + k];
  }
  a0 = wave_reduce(a0); a1 = wave_reduce(a1);
  a2 = wave_reduce(a2); a3 = wave_reduce(a3);
  if (lane == 0) {
    float* o = outv + (size_t)row * 4;
    o[0] = a0; o[1] = a1; o[2] = a2; o[3] = a3;
  }
}

// ---------------- C[M,N](bf16) = A_eff[M,K] @ B[K,N] ----------------
#define TM 64
#define TN 64
#define TK 16
__global__ __launch_bounds__(256) void gemm_tile(const void* __restrict__ A,
                                                 const int* __restrict__ mask,
                                                 const void* __restrict__ tok,
                                                 const void* __restrict__ B,
                                                 __hip_bfloat16* __restrict__ C,
                                                 int M, int N, int K,
                                                 const int* __restrict__ flag) {
  int f32 = flag[0];
  __shared__ float As[TK][TM + 4];
  __shared__ float Bs[TK][TN + 4];
  int t = threadIdx.x;
  int m0 = blockIdx.y * TM;
  int n0 = blockIdx.x * TN;
  int tm = (t & 15) * 4;
  int tn = (t >> 4) * 4;
  float acc[4][4] = {{0.f}};
  for (int k0 = 0; k0 < K; k0 += TK) {
#pragma unroll
    for (int i = 0; i < 4; ++i) {
      int lin = t + i * 256;  // TM*TK, m-major
      int m = lin / TK;
      int kk = lin % TK;
      int gm = m0 + m, gk = k0 + kk;
      float v = 0.f;
      if (gm < M && gk < K) {
        bool msk = (mask != nullptr) && (mask[gm] != 0);
        v = msk ? ldx(tok, gk, f32) : ldx(A, (size_t)gm * K + gk, f32);
      }
      As[kk][m] = v;
    }
#pragma unroll
    for (int i = 0; i < 4; ++i) {
      int lin = t + i * 256;  // TK*TN, kk-major
      int kk = lin / TN;
      int n = lin % TN;
      int gk = k0 + kk;
      float v = 0.f;
      if (gk < K) v = ldx(B, (size_t)gk * N + (n0 + n), f32);
      Bs[kk][n] = v;
    }
    __syncthreads();
#pragma unroll
    for (int kk = 0; kk < TK; ++kk) {
      float a0 = As[kk][tm + 0], a1 = As[kk][tm + 1], a2 = As[kk][tm + 2], a3 = As[kk][tm + 3];
      float b0 = Bs[kk][tn + 0], b1 = Bs[kk][tn + 1], b2 = Bs[kk][tn + 2], b3 = Bs[kk][tn + 3];
      acc[0][0] += a0 * b0; acc[0][1] += a0 * b1; acc[0][2] += a0 * b2; acc[0][3] += a0 * b3;
      acc[1][0] += a1 * b0; acc[1][1] += a1 * b1; acc[1][2] += a1 * b2; acc[1][3] += a1 * b3;
      acc[2][0] += a2 * b0; acc[2][1] += a2 * b1; acc[2][2] += a2 * b2; acc[2][3] += a2 * b3;
      acc[3][0] += a3 * b0; acc[3][1] += a3 * b1; acc[3][2] += a3 * b2; acc[3][3] += a3 * b3;
    }
    __syncthreads();
  }
#pragma unroll
  for (int i = 0; i < 4; ++i) {
    int gm = m0 + tm + i;
    if (gm < M) {
#pragma unroll
      for (int j = 0; j < 4; ++j)
        C[(size_t)gm * N + n0 + tn + j] = __float2bfloat16(acc[i][j]);
    }
  }
}

// ---------------- CSR build ----------------
__global__ void zero_i32(int* __restrict__ p, int n) {
  int i = blockIdx.x * 256 + threadIdx.x;
  if (i < n) p[i] = 0;
}
__global__ void zero_f32(float* __restrict__ p, int n) {
  int i = blockIdx.x * 256 + threadIdx.x;
  if (i < n) p[i] = 0.f;
}

__global__ void csr_count(const int* __restrict__ dst, int E, int nself, int* __restrict__ cnt) {
  int i = blockIdx.x * 256 + threadIdx.x;
  if (i >= E + nself) return;
  int d = (i < E) ? dst[i] : (i - E);
  atomicAdd(&cnt[d], 1);
}

// single-block exclusive scan (n up to ~30001)
__global__ __launch_bounds__(256) void scan_excl(const int* __restrict__ cnt,
                                                 int* __restrict__ rowptr, int n) {
  __shared__ int part[256];
  int t = threadIdx.x;
  int strip = (n + 255) / 256;
  int lo = min(t * strip, n), hi = min(lo + strip, n);
  int s = 0;
  for (int i = lo; i < hi; ++i) s += cnt[i];
  part[t] = s;
  __syncthreads();
  if (t == 0) {
    int run = 0;
    for (int i = 0; i < 256; ++i) { int v = part[i]; part[i] = run; run += v; }
  }
  __syncthreads();
  int run = part[t];
  for (int i = lo; i < hi; ++i) { rowptr[i] = run; run += cnt[i]; }
  if (hi == n) rowptr[n] = run;   // last non-empty strip writes total (benign dup)
}

__global__ void csr_fill(const int* __restrict__ src, const int* __restrict__ dst, int E, int nself,
                         const int* __restrict__ rowptr, int* __restrict__ fill,
                         int* __restrict__ eidx) {
  int i = blockIdx.x * 256 + threadIdx.x;
  if (i >= E + nself) return;
  int s, d;
  if (i < E) { s = src[i]; d = dst[i]; } else { s = d = i - E; }
  int pos = rowptr[d] + atomicAdd(&fill[d], 1);
  eidx[pos] = s;
}

// ---------------- fused GAT gather: bias + 2 relations + relu (+loss) ------
// One wave per dst node. es*/ed* indexed with stride 4 (component pre-offset).
// mode 1: write relu(acc) to out.  mode 2: masked sqdiff vs out -> parts.
__global__ __launch_bounds__(256) void gat_gather(
    const int* __restrict__ rp1, const int* __restrict__ ei1,
    const __hip_bfloat16* __restrict__ hs1,
    const float* __restrict__ es1, const float* __restrict__ ed1,
    const int* __restrict__ rp2, const int* __restrict__ ei2,
    const __hip_bfloat16* __restrict__ hs2,
    const float* __restrict__ es2, const float* __restrict__ ed2,
    const void* __restrict__ b1, const void* __restrict__ b2,
    int Nd, void* __restrict__ out, size_t base,
    const int* __restrict__ mask, float* __restrict__ parts, int mode,
    const int* __restrict__ flag) {
  int wid = (blockIdx.x * 256 + threadIdx.x) >> 6;
  int lane = threadIdx.x & 63;
  if (wid >= Nd) return;
  int f32 = flag[0];
  float acc[3][4];
#pragma unroll
  for (int j = 0; j < 3; ++j)
#pragma unroll
    for (int c = 0; c < 4; ++c) {
      int h = 4 * lane + 256 * j + c;
      acc[j][c] = ldx(b1, h, f32) + ldx(b2, h, f32);
    }

#pragma unroll
  for (int rel = 0; rel < 2; ++rel) {
    const int* rp = rel ? rp2 : rp1;
    const int* ei = rel ? ei2 : ei1;
    const __hip_bfloat16* hs = rel ? hs2 : hs1;
    const float* es = rel ? es2 : es1;
    const float* ed = rel ? ed2 : ed1;
    int lo = rp[wid], hi = rp[wid + 1];
    float edv = ed[4 * (size_t)wid];
    float s = 0.f;
    for (int e = lo + lane; e < hi; e += 64) {
      float v = es[4 * (size_t)ei[e]] + edv;
      v = (v >= 0.f) ? v : 0.2f * v;
      s += __expf(v);
    }
    s = wave_reduce(s);
    float inv = 1.f / (s + 1e-16f);
    for (int e = lo; e < hi; ++e) {
      int sn = ei[e];                       // broadcast load (wave-uniform)
      float v = es[4 * (size_t)sn] + edv;
      v = (v >= 0.f) ? v : 0.2f * v;
      float alpha = __expf(v) * inv;
      const ushort4* row = (const ushort4*)(hs + (size_t)sn * HDIM);
#pragma unroll
      for (int j = 0; j < 3; ++j) {
        ushort4 u = row[lane + 64 * j];
        acc[j][0] += alpha * b2f(u.x);
        acc[j][1] += alpha * b2f(u.y);
        acc[j][2] += alpha * b2f(u.z);
        acc[j][3] += alpha * b2f(u.w);
      }
    }
  }

  size_t rowbase = base + (size_t)wid * HDIM;
  if (mode == 1) {
#pragma unroll
    for (int j = 0; j < 3; ++j)
#pragma unroll
      for (int c = 0; c < 4; ++c) {
        int h = 4 * lane + 256 * j + c;
        float v = acc[j][c];
        stx(out, rowbase + h, f32, v > 0.f ? v : 0.f);
      }
  } else {
    float cpart = 0.f;
    bool m = mask[wid] != 0;
#pragma unroll
    for (int j = 0; j < 3; ++j)
#pragma unroll
      for (int c = 0; c < 4; ++c) {
        int h = 4 * lane + 256 * j + c;
        float v = acc[j][c];
        v = v > 0.f ? v : 0.f;
        if (m) {
          float d = ldx(out, rowbase + h, f32) - v;
          cpart += d * d;
        }
      }
    cpart = wave_reduce(cpart);
    if (lane == 0 && m) atomicAdd(&parts[wid & 2047], cpart);
  }
}

// ---------------- loss helpers ----------------
__global__ void mask_count(const int* __restrict__ mask, int n, float* __restrict__ cnt) {
  int i = blockIdx.x * 256 + threadIdx.x;
  float v = (i < n && mask[i] != 0) ? 1.f : 0.f;
  v = wave_reduce(v);
  __shared__ float red[4];
  if ((threadIdx.x & 63) == 0) red[threadIdx.x >> 6] = v;
  __syncthreads();
  if (threadIdx.x == 0) atomicAdd(cnt, red[0] + red[1] + red[2] + red[3]);
}

__global__ __launch_bounds__(256) void loss_final(const float* __restrict__ parts,
                                                  const float* __restrict__ cnts,
                                                  void* __restrict__ out, size_t off,
                                                  const int* __restrict__ flag) {
  float a = 0.f, b = 0.f;
  for (int i = threadIdx.x; i < 2048; i += 256) { a += parts[i]; b += parts[2048 + i]; }
  a = wave_reduce(a);
  b = wave_reduce(b);
  __shared__ float ra[4], rb[4];
  if ((threadIdx.x & 63) == 0) { ra[threadIdx.x >> 6] = a; rb[threadIdx.x >> 6] = b; }
  __syncthreads();
  if (threadIdx.x == 0) {
    float sd = ra[0] + ra[1] + ra[2] + ra[3];
    float st = rb[0] + rb[1] + rb[2] + rb[3];
    float loss = sd / (cnts[0] * (float)HDIM + 1e-16f) + st / (cnts[1] * (float)HDIM + 1e-16f);
    stx(out, off, flag[0], loss);
  }
}

// ---------------- host ----------------

extern "C" void kernel_launch(void* const* d_in, const int* in_sizes, int n_in,
                              void* d_out, int out_size, void* d_ws, size_t ws_size,
                              hipStream_t stream) {
  const void* drug_x    = d_in[0];
  const void* target_x  = d_in[1];
  const int* dd_src = (const int*)d_in[2];
  const int* dd_dst = (const int*)d_in[3];
  const int* dt_src = (const int*)d_in[4];
  const int* dt_dst = (const int*)d_in[5];
  const int* tt_src = (const int*)d_in[6];
  const int* tt_dst = (const int*)d_in[7];
  const int* drug_mask   = (const int*)d_in[8];
  const int* target_mask = (const int*)d_in[9];
  const void* mask_drug   = d_in[10];
  const void* mask_target = d_in[11];
  const void* Wsrc_dd = d_in[12]; const void* Wdst_dd = d_in[13];
  const void* asrc_dd = d_in[14]; const void* adst_dd = d_in[15];
  const void* b_dd    = d_in[16];
  const void* Wsrc_dt = d_in[17]; const void* Wdst_dt = d_in[18];
  const void* asrc_dt = d_in[19]; const void* adst_dt = d_in[20];
  const void* b_dt    = d_in[21];
  const void* Wsrc_rv = d_in[22]; const void* Wdst_rv = d_in[23];
  const void* asrc_rv = d_in[24]; const void* adst_rv = d_in[25];
  const void* b_rv    = d_in[26];
  const void* Wsrc_tt = d_in[27]; const void* Wdst_tt = d_in[28];
  const void* asrc_tt = d_in[29]; const void* adst_tt = d_in[30];
  const void* b_tt    = d_in[31];

  // workspace bump allocator (256B aligned)
  char* p = (char*)d_ws;
  auto alloc = [&](size_t bytes) -> void* {
    void* r = (void*)p;
    p += (bytes + 255) & ~(size_t)255;
    return r;
  };
  __hip_bfloat16* hs_dd = (__hip_bfloat16*)alloc((size_t)ND * HDIM * 2);
  __hip_bfloat16* hs_rv = (__hip_bfloat16*)alloc((size_t)NT * HDIM * 2);
  __hip_bfloat16* hs_dt = (__hip_bfloat16*)alloc((size_t)ND * HDIM * 2);
  __hip_bfloat16* hs_tt = (__hip_bfloat16*)alloc((size_t)NT * HDIM * 2);
  float* dvec = (float*)alloc((size_t)ND * 4 * 4);   // {es_dd, ed_dd, ed_rv, es_dt}
  float* tvec = (float*)alloc((size_t)NT * 4 * 4);   // {es_rv, ed_dt, es_tt, ed_tt}
  int* rp_dd = (int*)alloc((size_t)(ND + 1) * 4);
  int* rp_rv = (int*)alloc((size_t)(ND + 1) * 4);
  int* rp_dt = (int*)alloc((size_t)(NT + 1) * 4);
  int* rp_tt = (int*)alloc((size_t)(NT + 1) * 4);
  int* ei_dd = (int*)alloc((size_t)(EDD + ND) * 4);
  int* ei_rv = (int*)alloc((size_t)EDT * 4);
  int* ei_dt = (int*)alloc((size_t)EDT * 4);
  int* ei_tt = (int*)alloc((size_t)(ETT + NT) * 4);
  int* cnt   = (int*)alloc((size_t)ND * 4);
  int* fill  = (int*)alloc((size_t)ND * 4);
  float* vaD = (float*)alloc((size_t)4 * FD * 4);
  float* vaT = (float*)alloc((size_t)4 * FT * 4);
  float* parts = (float*)alloc((size_t)(4096 + 2) * 4);  // [2048 d][2048 t][cnt_d][cnt_t]
  float* cnts  = parts + 4096;
  int*   flag  = (int*)alloc(256);

  // 1) dtype sniff
  sniff<<<1, 256, 0, stream>>>(drug_x, flag);

  // 2) zero loss partials + mask counters
  zero_f32<<<(4098 + 255) / 256, 256, 0, stream>>>(parts, 4098);
  mask_count<<<(ND + 255) / 256, 256, 0, stream>>>(drug_mask, ND, cnts + 0);
  mask_count<<<(NT + 255) / 256, 256, 0, stream>>>(target_mask, NT, cnts + 1);

  // 3) va vectors (packed per node type)
  struct { const void* W; const void* a; int fin; float* out; } vas[8] = {
    {Wsrc_dd, asrc_dd, FD, vaD + 0 * FD}, {Wdst_dd, adst_dd, FD, vaD + 1 * FD},
    {Wdst_rv, adst_rv, FD, vaD + 2 * FD}, {Wsrc_dt, asrc_dt, FD, vaD + 3 * FD},
    {Wsrc_rv, asrc_rv, FT, vaT + 0 * FT}, {Wdst_dt, adst_dt, FT, vaT + 1 * FT},
    {Wsrc_tt, asrc_tt, FT, vaT + 2 * FT}, {Wdst_tt, adst_tt, FT, vaT + 3 * FT},
  };
  for (int i = 0; i < 8; ++i)
    wa_dot<<<(vas[i].fin * 64 + 255) / 256, 256, 0, stream>>>(vas[i].W, vas[i].a,
                                                              vas[i].out, vas[i].fin, flag);

  // 4) CSR build (once; reused by both layers)
  auto build_csr = [&](const int* srcI, const int* dstI, int E, int nself, int Nd,
                       int* rowptr, int* eidx) {
    int ET = E + nself;
    zero_i32<<<(Nd + 255) / 256, 256, 0, stream>>>(cnt, Nd);
    csr_count<<<(ET + 255) / 256, 256, 0, stream>>>(dstI, E, nself, cnt);
    scan_excl<<<1, 256, 0, stream>>>(cnt, rowptr, Nd);
    zero_i32<<<(Nd + 255) / 256, 256, 0, stream>>>(fill, Nd);
    csr_fill<<<(ET + 255) / 256, 256, 0, stream>>>(srcI, dstI, E, nself, rowptr, fill, eidx);
  };
  build_csr(dd_src, dd_dst, EDD, ND, ND, rp_dd, ei_dd);     // drug <- drug (+self)
  build_csr(dt_dst, dt_src, EDT, 0,  ND, rp_rv, ei_rv);     // drug <- target (rev)
  build_csr(dt_src, dt_dst, EDT, 0,  NT, rp_dt, ei_dt);     // target <- drug
  build_csr(tt_src, tt_dst, ETT, NT, NT, rp_tt, ei_tt);     // target <- target (+self)

  size_t baseT = (size_t)ND * HDIM;
  size_t baseL = baseT + (size_t)NT * HDIM;

  // 5) per-layer pipeline
  auto run_layer = [&](const int* mD, const int* mT, int mode) {
    row_dot4<<<(ND + 3) / 4, 256, 0, stream>>>(drug_x, mD, mask_drug, vaD, dvec, ND, FD, flag);
    row_dot4<<<(NT + 3) / 4, 256, 0, stream>>>(target_x, mT, mask_target, vaT, tvec, NT, FT, flag);
    dim3 gD(HDIM / TN, (ND + TM - 1) / TM);
    dim3 gT(HDIM / TN, (NT + TM - 1) / TM);
    gemm_tile<<<gD, 256, 0, stream>>>(drug_x, mD, mask_drug, Wsrc_dd, hs_dd, ND, HDIM, FD, flag);
    gemm_tile<<<gT, 256, 0, stream>>>(target_x, mT, mask_target, Wsrc_rv, hs_rv, NT, HDIM, FT, flag);
    gemm_tile<<<gD, 256, 0, stream>>>(drug_x, mD, mask_drug, Wsrc_dt, hs_dt, ND, HDIM, FD, flag);
    gemm_tile<<<gT, 256, 0, stream>>>(target_x, mT, mask_target, Wsrc_tt, hs_tt, NT, HDIM, FT, flag);
    // drugs: rel1 = dd (es=dvec.0, ed=dvec.1), rel2 = rv (es=tvec.0, ed=dvec.2)
    gat_gather<<<(ND + 3) / 4, 256, 0, stream>>>(
        rp_dd, ei_dd, hs_dd, dvec + 0, dvec + 1,
        rp_rv, ei_rv, hs_rv, tvec + 0, dvec + 2,
        b_dd, b_rv, ND, d_out, 0, drug_mask, parts, mode, flag);
    // targets: rel1 = dt (es=dvec.3, ed=tvec.1), rel2 = tt (es=tvec.2, ed=tvec.3)
    gat_gather<<<(NT + 3) / 4, 256, 0, stream>>>(
        rp_dt, ei_dt, hs_dt, dvec + 3, tvec + 1,
        rp_tt, ei_tt, hs_tt, tvec + 2, tvec + 3,
        b_dt, b_tt, NT, d_out, baseT, target_mask, parts + 2048, mode, flag);
  };

  run_layer(nullptr, nullptr, 1);          // layer 1: write relu outputs
  run_layer(drug_mask, target_mask, 2);    // layer 2: masked sqdiff vs layer-1 out
  loss_final<<<1, 256, 0, stream>>>(parts, cnts, d_out, baseL, flag);
}

// Round 4
// 1585.027 us; speedup vs baseline: 6.1798x; 2.4565x over previous
//
#include <hip/hip_runtime.h>
#include <hip/hip_bf16.h>

#define ND 30000
#define NT 15000
#define FD 200
#define FT 570
#define HDIM 768
#define EDD 300000
#define EDT 400000
#define ETT 200000

#define KPD 256   // FD padded to x64
#define KPT 576   // FT padded to x64

typedef __attribute__((ext_vector_type(8))) short short8;
typedef __attribute__((ext_vector_type(4))) float float4v;

// ---------------- dtype-adaptive load/store ----------------
// flag[0]: 0 = harness float tensors are bf16, 1 = fp32.

__device__ __forceinline__ float ldx(const void* p, size_t i, int f32) {
  return f32 ? ((const float*)p)[i]
             : __bfloat162float(((const __hip_bfloat16*)p)[i]);
}
__device__ __forceinline__ void stx(void* p, size_t i, int f32, float v) {
  if (f32) ((float*)p)[i] = v;
  else     ((__hip_bfloat16*)p)[i] = __float2bfloat16(v);
}
__device__ __forceinline__ float b2f(unsigned short u) {
  return __uint_as_float(((unsigned)u) << 16);
}
__device__ __forceinline__ unsigned short f2b(float f) {
  __hip_bfloat16 h = __float2bfloat16(f);
  return *(unsigned short*)&h;
}

__device__ __forceinline__ float wave_reduce(float v) {
#pragma unroll
  for (int off = 32; off > 0; off >>= 1) v += __shfl_xor(v, off, 64);
  return v;
}

// ---------------- dtype sniffer ----------------
__global__ void sniff(const void* x, int* flag) {
  int t = threadIdx.x;
  float cnt = 0.f;
  for (int i = t; i < 8192; i += 256) {
    float v = __bfloat162float(((const __hip_bfloat16*)x)[i]);
    if (!(fabsf(v) < 100.f)) cnt += 1.f;  // true for NaN too
  }
  cnt = wave_reduce(cnt);
  __shared__ float red[4];
  if ((t & 63) == 0) red[t >> 6] = cnt;
  __syncthreads();
  if (t == 0) flag[0] = (red[0] + red[1] + red[2] + red[3] > 256.f) ? 1 : 0;
}

// ---------------- va[k] = sum_h W[k,h]*a[h], one wave per k ----------------
__global__ __launch_bounds__(256) void wa_dot(const void* __restrict__ W, const void* __restrict__ a,
                                              float* __restrict__ outv, int fin,
                                              const int* __restrict__ flag) {
  int f32 = flag[0];
  int k = (blockIdx.x * 256 + threadIdx.x) >> 6;
  int lane = threadIdx.x & 63;
  if (k >= fin) return;
  float acc = 0.f;
  for (int h = lane; h < HDIM; h += 64)
    acc += ldx(W, (size_t)k * HDIM + h, f32) * ldx(a, h, f32);
  acc = wave_reduce(acc);
  if (lane == 0) outv[k] = acc;
}

// ---------- 4 dots per row (shared x read), one wave per row ----------
__global__ __launch_bounds__(256) void row_dot4(const void* __restrict__ x,
                                                const int* __restrict__ mask,
                                                const void* __restrict__ tok,
                                                const float* __restrict__ va,
                                                float* __restrict__ outv, int N, int K,
                                                const int* __restrict__ flag) {
  int f32 = flag[0];
  int row = (blockIdx.x * 256 + threadIdx.x) >> 6;
  int lane = threadIdx.x & 63;
  if (row >= N) return;
  bool msk = (mask != nullptr) && (mask[row] != 0);
  float a0 = 0.f, a1 = 0.f, a2 = 0.f, a3 = 0.f;
  for (int k = lane; k < K; k += 64) {
    float v = msk ? ldx(tok, k, f32) : ldx(x, (size_t)row * K + k, f32);
    a0 += v * va[k];
    a1 += v * va[K + k];
    a2 += v * va[2 * K + k];
    a3 += v * va[3 * K + k];
  }
  a0 = wave_reduce(a0); a1 = wave_reduce(a1);
  a2 = wave_reduce(a2); a3 = wave_reduce(a3);
  if (lane == 0) {
    float* o = outv + (size_t)row * 4;
    o[0] = a0; o[1] = a1; o[2] = a2; o[3] = a3;
  }
}

// ---------------- pack A: x_eff -> bf16 [M][Kp], zero-padded K ----------------
__global__ __launch_bounds__(256) void pack_a(const void* __restrict__ x,
                                              const int* __restrict__ mask,
                                              const void* __restrict__ tok,
                                              unsigned short* __restrict__ Aout,
                                              int M, int K, int Kp,
                                              const int* __restrict__ flag) {
  int f32 = flag[0];
  long long gid = (long long)blockIdx.x * 256 + threadIdx.x;
  long long total = (long long)M * Kp / 4;
  if (gid >= total) return;
  long long e0 = gid * 4;
  int row = (int)(e0 / Kp);
  int k = (int)(e0 % Kp);
  bool msk = (mask != nullptr) && (mask[row] != 0);
  ushort4 o;
  unsigned short r[4];
#pragma unroll
  for (int c = 0; c < 4; ++c) {
    int kk = k + c;
    float f = 0.f;
    if (kk < K) f = msk ? ldx(tok, kk, f32) : ldx(x, (size_t)row * K + kk, f32);
    r[c] = f2b(f);
  }
  o.x = r[0]; o.y = r[1]; o.z = r[2]; o.w = r[3];
  *(ushort4*)(Aout + e0) = o;
}

// ---------------- pack B: [W1 | W2] (K x 768 each) -> bf16 B^T [1536][Kp] ------
__global__ __launch_bounds__(256) void pack_bT(const void* __restrict__ W1,
                                               const void* __restrict__ W2,
                                               unsigned short* __restrict__ Bout,
                                               int K, int Kp, const int* __restrict__ flag) {
  int f32 = flag[0];
  long long gid = (long long)blockIdx.x * 256 + threadIdx.x;
  long long total = (long long)2 * HDIM * Kp / 4;
  if (gid >= total) return;
  long long e0 = gid * 4;
  int n = (int)(e0 / Kp);
  int k = (int)(e0 % Kp);
  const void* W = (n < HDIM) ? W1 : W2;
  int nn = (n < HDIM) ? n : n - HDIM;
  ushort4 o;
  unsigned short r[4];
#pragma unroll
  for (int c = 0; c < 4; ++c) {
    int kk = k + c;
    float f = 0.f;
    if (kk < K) f = ldx(W, (size_t)kk * HDIM + nn, f32);
    r[c] = f2b(f);
  }
  o.x = r[0]; o.y = r[1]; o.z = r[2]; o.w = r[3];
  *(ushort4*)(Bout + e0) = o;
}

// ---------------- MFMA GEMM: C[M,1536] = A[M,Kp] @ B^T[1536,Kp] ----------------
// C cols 0..767 -> C1, 768..1535 -> C2 (both [M][768] bf16).
#define BM 128
#define BN 128
#define BK 64
#define LDK 72   // LDS k-stride (elements): +8 pad -> row stride 144B = 4-bank rotate

__global__ __launch_bounds__(256) void gemm_mfma(const unsigned short* __restrict__ A,
                                                 const unsigned short* __restrict__ Bt,
                                                 __hip_bfloat16* __restrict__ C1,
                                                 __hip_bfloat16* __restrict__ C2,
                                                 int M, int Kp) {
  __shared__ unsigned short Als[BM * LDK];
  __shared__ unsigned short Bls[BN * LDK];
  int t = threadIdx.x;
  int wave = t >> 6, lane = t & 63;
  int quad = lane >> 4, l15 = lane & 15;
  int wrow = (wave & 1) * 64, wcol = (wave >> 1) * 64;
  int m0 = blockIdx.y * BM;
  int n0 = blockIdx.x * BN;
  float4v acc[4][4];
#pragma unroll
  for (int i = 0; i < 4; ++i)
#pragma unroll
    for (int j = 0; j < 4; ++j) acc[i][j] = (float4v){0.f, 0.f, 0.f, 0.f};

  for (int k0 = 0; k0 < Kp; k0 += BK) {
    // stage A tile: 128 rows x 64 k (1024 16B-chunks, 4 per thread)
#pragma unroll
    for (int i = 0; i < 4; ++i) {
      int idx = t + i * 256;
      int row = idx >> 3, c = idx & 7;
      uint4 v = make_uint4(0u, 0u, 0u, 0u);
      int gm = m0 + row;
      if (gm < M) v = *(const uint4*)(A + (size_t)gm * Kp + k0 + c * 8);
      *(uint4*)(Als + row * LDK + c * 8) = v;
    }
    // stage B tile (N rows always valid: 1536 % 128 == 0)
#pragma unroll
    for (int i = 0; i < 4; ++i) {
      int idx = t + i * 256;
      int row = idx >> 3, c = idx & 7;
      uint4 v = *(const uint4*)(Bt + (size_t)(n0 + row) * Kp + k0 + c * 8);
      *(uint4*)(Bls + row * LDK + c * 8) = v;
    }
    __syncthreads();
#pragma unroll
    for (int kk = 0; kk < 2; ++kk) {
      int koff = kk * 32 + quad * 8;
      short8 a[4], b[4];
#pragma unroll
      for (int i = 0; i < 4; ++i)
        a[i] = *(const short8*)(Als + (wrow + i * 16 + l15) * LDK + koff);
#pragma unroll
      for (int j = 0; j < 4; ++j)
        b[j] = *(const short8*)(Bls + (wcol + j * 16 + l15) * LDK + koff);
#pragma unroll
      for (int i = 0; i < 4; ++i)
#pragma unroll
        for (int j = 0; j < 4; ++j)
          acc[i][j] = __builtin_amdgcn_mfma_f32_16x16x32_bf16(a[i], b[j], acc[i][j], 0, 0, 0);
    }
    __syncthreads();
  }

  // epilogue: C/D layout col=lane&15, row=quad*4+reg
  bool second = (n0 >= HDIM);              // block-uniform (768 % 128 == 0)
  __hip_bfloat16* C = second ? C2 : C1;
  int nbase = second ? (n0 - HDIM) : n0;
#pragma unroll
  for (int i = 0; i < 4; ++i) {
    int mrow = m0 + wrow + i * 16 + quad * 4;
#pragma unroll
    for (int j = 0; j < 4; ++j) {
      int n = nbase + wcol + j * 16 + l15;
#pragma unroll
      for (int r = 0; r < 4; ++r) {
        int m = mrow + r;
        if (m < M) C[(size_t)m * HDIM + n] = __float2bfloat16(acc[i][j][r]);
      }
    }
  }
}

// ---------------- CSR build ----------------
__global__ void zero_i32(int* __restrict__ p, int n) {
  int i = blockIdx.x * 256 + threadIdx.x;
  if (i < n) p[i] = 0;
}
__global__ void zero_f32(float* __restrict__ p, int n) {
  int i = blockIdx.x * 256 + threadIdx.x;
  if (i < n) p[i] = 0.f;
}

__global__ void csr_count(const int* __restrict__ dst, int E, int nself, int* __restrict__ cnt) {
  int i = blockIdx.x * 256 + threadIdx.x;
  if (i >= E + nself) return;
  int d = (i < E) ? dst[i] : (i - E);
  atomicAdd(&cnt[d], 1);
}

__global__ __launch_bounds__(256) void scan_excl(const int* __restrict__ cnt,
                                                 int* __restrict__ rowptr, int n) {
  __shared__ int part[256];
  int t = threadIdx.x;
  int strip = (n + 255) / 256;
  int lo = min(t * strip, n), hi = min(lo + strip, n);
  int s = 0;
  for (int i = lo; i < hi; ++i) s += cnt[i];
  part[t] = s;
  __syncthreads();
  if (t == 0) {
    int run = 0;
    for (int i = 0; i < 256; ++i) { int v = part[i]; part[i] = run; run += v; }
  }
  __syncthreads();
  int run = part[t];
  for (int i = lo; i < hi; ++i) { rowptr[i] = run; run += cnt[i]; }
  if (hi == n) rowptr[n] = run;
}

__global__ void csr_fill(const int* __restrict__ src, const int* __restrict__ dst, int E, int nself,
                         const int* __restrict__ rowptr, int* __restrict__ fill,
                         int* __restrict__ eidx) {
  int i = blockIdx.x * 256 + threadIdx.x;
  if (i >= E + nself) return;
  int s, d;
  if (i < E) { s = src[i]; d = dst[i]; } else { s = d = i - E; }
  int pos = rowptr[d] + atomicAdd(&fill[d], 1);
  eidx[pos] = s;
}

// ---------------- fused GAT gather ----------------
__global__ __launch_bounds__(256) void gat_gather(
    const int* __restrict__ rp1, const int* __restrict__ ei1,
    const __hip_bfloat16* __restrict__ hs1,
    const float* __restrict__ es1, const float* __restrict__ ed1,
    const int* __restrict__ rp2, const int* __restrict__ ei2,
    const __hip_bfloat16* __restrict__ hs2,
    const float* __restrict__ es2, const float* __restrict__ ed2,
    const void* __restrict__ b1, const void* __restrict__ b2,
    int Nd, void* __restrict__ out, size_t base,
    const int* __restrict__ mask, float* __restrict__ parts, int mode,
    const int* __restrict__ flag) {
  int wid = (blockIdx.x * 256 + threadIdx.x) >> 6;
  int lane = threadIdx.x & 63;
  if (wid >= Nd) return;
  int f32 = flag[0];
  float acc[3][4];
#pragma unroll
  for (int j = 0; j < 3; ++j)
#pragma unroll
    for (int c = 0; c < 4; ++c) {
      int h = 4 * lane + 256 * j + c;
      acc[j][c] = ldx(b1, h, f32) + ldx(b2, h, f32);
    }

#pragma unroll
  for (int rel = 0; rel < 2; ++rel) {
    const int* rp = rel ? rp2 : rp1;
    const int* ei = rel ? ei2 : ei1;
    const __hip_bfloat16* hs = rel ? hs2 : hs1;
    const float* es = rel ? es2 : es1;
    const float* ed = rel ? ed2 : ed1;
    int lo = rp[wid], hi = rp[wid + 1];
    float edv = ed[4 * (size_t)wid];
    float s = 0.f;
    for (int e = lo + lane; e < hi; e += 64) {
      float v = es[4 * (size_t)ei[e]] + edv;
      v = (v >= 0.f) ? v : 0.2f * v;
      s += __expf(v);
    }
    s = wave_reduce(s);
    float inv = 1.f / (s + 1e-16f);
    for (int e = lo; e < hi; ++e) {
      int sn = ei[e];
      float v = es[4 * (size_t)sn] + edv;
      v = (v >= 0.f) ? v : 0.2f * v;
      float alpha = __expf(v) * inv;
      const ushort4* row = (const ushort4*)(hs + (size_t)sn * HDIM);
#pragma unroll
      for (int j = 0; j < 3; ++j) {
        ushort4 u = row[lane + 64 * j];
        acc[j][0] += alpha * b2f(u.x);
        acc[j][1] += alpha * b2f(u.y);
        acc[j][2] += alpha * b2f(u.z);
        acc[j][3] += alpha * b2f(u.w);
      }
    }
  }

  size_t rowbase = base + (size_t)wid * HDIM;
  if (mode == 1) {
#pragma unroll
    for (int j = 0; j < 3; ++j)
#pragma unroll
      for (int c = 0; c < 4; ++c) {
        int h = 4 * lane + 256 * j + c;
        float v = acc[j][c];
        stx(out, rowbase + h, f32, v > 0.f ? v : 0.f);
      }
  } else {
    float cpart = 0.f;
    bool m = mask[wid] != 0;
#pragma unroll
    for (int j = 0; j < 3; ++j)
#pragma unroll
      for (int c = 0; c < 4; ++c) {
        int h = 4 * lane + 256 * j + c;
        float v = acc[j][c];
        v = v > 0.f ? v : 0.f;
        if (m) {
          float d = ldx(out, rowbase + h, f32) - v;
          cpart += d * d;
        }
      }
    cpart = wave_reduce(cpart);
    if (lane == 0 && m) atomicAdd(&parts[wid & 2047], cpart);
  }
}

// ---------------- loss helpers ----------------
__global__ void mask_count(const int* __restrict__ mask, int n, float* __restrict__ cnt) {
  int i = blockIdx.x * 256 + threadIdx.x;
  float v = (i < n && mask[i] != 0) ? 1.f : 0.f;
  v = wave_reduce(v);
  __shared__ float red[4];
  if ((threadIdx.x & 63) == 0) red[threadIdx.x >> 6] = v;
  __syncthreads();
  if (threadIdx.x == 0) atomicAdd(cnt, red[0] + red[1] + red[2] + red[3]);
}

__global__ __launch_bounds__(256) void loss_final(const float* __restrict__ parts,
                                                  const float* __restrict__ cnts,
                                                  void* __restrict__ out, size_t off,
                                                  const int* __restrict__ flag) {
  float a = 0.f, b = 0.f;
  for (int i = threadIdx.x; i < 2048; i += 256) { a += parts[i]; b += parts[2048 + i]; }
  a = wave_reduce(a);
  b = wave_reduce(b);
  __shared__ float ra[4], rb[4];
  if ((threadIdx.x & 63) == 0) { ra[threadIdx.x >> 6] = a; rb[threadIdx.x >> 6] = b; }
  __syncthreads();
  if (threadIdx.x == 0) {
    float sd = ra[0] + ra[1] + ra[2] + ra[3];
    float st = rb[0] + rb[1] + rb[2] + rb[3];
    float loss = sd / (cnts[0] * (float)HDIM + 1e-16f) + st / (cnts[1] * (float)HDIM + 1e-16f);
    stx(out, off, flag[0], loss);
  }
}

// ---------------- host ----------------

extern "C" void kernel_launch(void* const* d_in, const int* in_sizes, int n_in,
                              void* d_out, int out_size, void* d_ws, size_t ws_size,
                              hipStream_t stream) {
  const void* drug_x    = d_in[0];
  const void* target_x  = d_in[1];
  const int* dd_src = (const int*)d_in[2];
  const int* dd_dst = (const int*)d_in[3];
  const int* dt_src = (const int*)d_in[4];
  const int* dt_dst = (const int*)d_in[5];
  const int* tt_src = (const int*)d_in[6];
  const int* tt_dst = (const int*)d_in[7];
  const int* drug_mask   = (const int*)d_in[8];
  const int* target_mask = (const int*)d_in[9];
  const void* mask_drug   = d_in[10];
  const void* mask_target = d_in[11];
  const void* Wsrc_dd = d_in[12]; const void* Wdst_dd = d_in[13];
  const void* asrc_dd = d_in[14]; const void* adst_dd = d_in[15];
  const void* b_dd    = d_in[16];
  const void* Wsrc_dt = d_in[17]; const void* Wdst_dt = d_in[18];
  const void* asrc_dt = d_in[19]; const void* adst_dt = d_in[20];
  const void* b_dt    = d_in[21];
  const void* Wsrc_rv = d_in[22]; const void* Wdst_rv = d_in[23];
  const void* asrc_rv = d_in[24]; const void* adst_rv = d_in[25];
  const void* b_rv    = d_in[26];
  const void* Wsrc_tt = d_in[27]; const void* Wdst_tt = d_in[28];
  const void* asrc_tt = d_in[29]; const void* adst_tt = d_in[30];
  const void* b_tt    = d_in[31];

  char* p = (char*)d_ws;
  auto alloc = [&](size_t bytes) -> void* {
    void* r = (void*)p;
    p += (bytes + 255) & ~(size_t)255;
    return r;
  };
  __hip_bfloat16* hs_dd = (__hip_bfloat16*)alloc((size_t)ND * HDIM * 2);
  __hip_bfloat16* hs_rv = (__hip_bfloat16*)alloc((size_t)NT * HDIM * 2);
  __hip_bfloat16* hs_dt = (__hip_bfloat16*)alloc((size_t)ND * HDIM * 2);
  __hip_bfloat16* hs_tt = (__hip_bfloat16*)alloc((size_t)NT * HDIM * 2);
  unsigned short* Ad = (unsigned short*)alloc((size_t)ND * KPD * 2);
  unsigned short* At = (unsigned short*)alloc((size_t)NT * KPT * 2);
  unsigned short* Bd = (unsigned short*)alloc((size_t)2 * HDIM * KPD * 2);
  unsigned short* Bt = (unsigned short*)alloc((size_t)2 * HDIM * KPT * 2);
  float* dvec = (float*)alloc((size_t)ND * 4 * 4);   // {es_dd, ed_dd, ed_rv, es_dt}
  float* tvec = (float*)alloc((size_t)NT * 4 * 4);   // {es_rv, ed_dt, es_tt, ed_tt}
  int* rp_dd = (int*)alloc((size_t)(ND + 1) * 4);
  int* rp_rv = (int*)alloc((size_t)(ND + 1) * 4);
  int* rp_dt = (int*)alloc((size_t)(NT + 1) * 4);
  int* rp_tt = (int*)alloc((size_t)(NT + 1) * 4);
  int* ei_dd = (int*)alloc((size_t)(EDD + ND) * 4);
  int* ei_rv = (int*)alloc((size_t)EDT * 4);
  int* ei_dt = (int*)alloc((size_t)EDT * 4);
  int* ei_tt = (int*)alloc((size_t)(ETT + NT) * 4);
  int* cnt   = (int*)alloc((size_t)ND * 4);
  int* fill  = (int*)alloc((size_t)ND * 4);
  float* vaD = (float*)alloc((size_t)4 * FD * 4);
  float* vaT = (float*)alloc((size_t)4 * FT * 4);
  float* parts = (float*)alloc((size_t)(4096 + 2) * 4);
  float* cnts  = parts + 4096;
  int*   flag  = (int*)alloc(256);

  // 1) dtype sniff
  sniff<<<1, 256, 0, stream>>>(drug_x, flag);

  // 2) zero loss partials + mask counters
  zero_f32<<<(4098 + 255) / 256, 256, 0, stream>>>(parts, 4098);
  mask_count<<<(ND + 255) / 256, 256, 0, stream>>>(drug_mask, ND, cnts + 0);
  mask_count<<<(NT + 255) / 256, 256, 0, stream>>>(target_mask, NT, cnts + 1);

  // 3) va vectors
  struct { const void* W; const void* a; int fin; float* out; } vas[8] = {
    {Wsrc_dd, asrc_dd, FD, vaD + 0 * FD}, {Wdst_dd, adst_dd, FD, vaD + 1 * FD},
    {Wdst_rv, adst_rv, FD, vaD + 2 * FD}, {Wsrc_dt, asrc_dt, FD, vaD + 3 * FD},
    {Wsrc_rv, asrc_rv, FT, vaT + 0 * FT}, {Wdst_dt, adst_dt, FT, vaT + 1 * FT},
    {Wsrc_tt, asrc_tt, FT, vaT + 2 * FT}, {Wdst_tt, adst_tt, FT, vaT + 3 * FT},
  };
  for (int i = 0; i < 8; ++i)
    wa_dot<<<(vas[i].fin * 64 + 255) / 256, 256, 0, stream>>>(vas[i].W, vas[i].a,
                                                              vas[i].out, vas[i].fin, flag);

  // 4) pack weights (once; same for both layers): drug B = [Wsrc_dd | Wsrc_dt],
  //    target B = [Wsrc_rv | Wsrc_tt]
  {
    long long tb = (long long)2 * HDIM * KPD / 4;
    pack_bT<<<(int)((tb + 255) / 256), 256, 0, stream>>>(Wsrc_dd, Wsrc_dt, Bd, FD, KPD, flag);
    tb = (long long)2 * HDIM * KPT / 4;
    pack_bT<<<(int)((tb + 255) / 256), 256, 0, stream>>>(Wsrc_rv, Wsrc_tt, Bt, FT, KPT, flag);
  }

  // 5) CSR build (once; reused by both layers)
  auto build_csr = [&](const int* srcI, const int* dstI, int E, int nself, int Nd,
                       int* rowptr, int* eidx) {
    int ET = E + nself;
    zero_i32<<<(Nd + 255) / 256, 256, 0, stream>>>(cnt, Nd);
    csr_count<<<(ET + 255) / 256, 256, 0, stream>>>(dstI, E, nself, cnt);
    scan_excl<<<1, 256, 0, stream>>>(cnt, rowptr, Nd);
    zero_i32<<<(Nd + 255) / 256, 256, 0, stream>>>(fill, Nd);
    csr_fill<<<(ET + 255) / 256, 256, 0, stream>>>(srcI, dstI, E, nself, rowptr, fill, eidx);
  };
  build_csr(dd_src, dd_dst, EDD, ND, ND, rp_dd, ei_dd);
  build_csr(dt_dst, dt_src, EDT, 0,  ND, rp_rv, ei_rv);
  build_csr(dt_src, dt_dst, EDT, 0,  NT, rp_dt, ei_dt);
  build_csr(tt_src, tt_dst, ETT, NT, NT, rp_tt, ei_tt);

  size_t baseT = (size_t)ND * HDIM;
  size_t baseL = baseT + (size_t)NT * HDIM;

  // 6) per-layer pipeline
  auto run_layer = [&](const int* mD, const int* mT, int mode) {
    row_dot4<<<(ND + 3) / 4, 256, 0, stream>>>(drug_x, mD, mask_drug, vaD, dvec, ND, FD, flag);
    row_dot4<<<(NT + 3) / 4, 256, 0, stream>>>(target_x, mT, mask_target, vaT, tvec, NT, FT, flag);
    {
      long long ta = (long long)ND * KPD / 4;
      pack_a<<<(int)((ta + 255) / 256), 256, 0, stream>>>(drug_x, mD, mask_drug, Ad, ND, FD, KPD, flag);
      ta = (long long)NT * KPT / 4;
      pack_a<<<(int)((ta + 255) / 256), 256, 0, stream>>>(target_x, mT, mask_target, At, NT, FT, KPT, flag);
    }
    dim3 gD(2 * HDIM / BN, (ND + BM - 1) / BM);
    dim3 gT(2 * HDIM / BN, (NT + BM - 1) / BM);
    gemm_mfma<<<gD, 256, 0, stream>>>(Ad, Bd, hs_dd, hs_dt, ND, KPD);
    gemm_mfma<<<gT, 256, 0, stream>>>(At, Bt, hs_rv, hs_tt, NT, KPT);
    // drugs: rel1 = dd (es=dvec.0, ed=dvec.1), rel2 = rv (es=tvec.0, ed=dvec.2)
    gat_gather<<<(ND + 3) / 4, 256, 0, stream>>>(
        rp_dd, ei_dd, hs_dd, dvec + 0, dvec + 1,
        rp_rv, ei_rv, hs_rv, tvec + 0, dvec + 2,
        b_dd, b_rv, ND, d_out, 0, drug_mask, parts, mode, flag);
    // targets: rel1 = dt (es=dvec.3, ed=tvec.1), rel2 = tt (es=tvec.2, ed=tvec.3)
    gat_gather<<<(NT + 3) / 4, 256, 0, stream>>>(
        rp_dt, ei_dt, hs_dt, dvec + 3, tvec + 1,
        rp_tt, ei_tt, hs_tt, tvec + 2, tvec + 3,
        b_dt, b_tt, NT, d_out, baseT, target_mask, parts + 2048, mode, flag);
  };

  run_layer(nullptr, nullptr, 1);          // layer 1
  run_layer(drug_mask, target_mask, 2);    // layer 2 + fused loss
  loss_final<<<1, 256, 0, stream>>>(parts, cnts, d_out, baseL, flag);
}